// Round 3
// baseline (813.793 us; speedup 1.0000x reference)
//
#include <hip/hip_runtime.h>
#include <hip/hip_bf16.h>
#include <stdint.h>

typedef unsigned short u16;
typedef __bf16 bf16x8 __attribute__((ext_vector_type(8)));
typedef float floatx4 __attribute__((ext_vector_type(4)));

#define B_SZ 64
#define T_SZ 1024
#define NK 500

// f32 -> bf16, round-to-nearest-even
__device__ __forceinline__ u16 f2bf(float f) {
    union { float f; uint32_t u; } v; v.f = f;
    uint32_t u = v.u;
    u += 0x7FFFu + ((u >> 16) & 1u);
    return (u16)(u >> 16);
}

// stable 2-way logsumexp
__device__ __forceinline__ float lse2(float a, float b) {
    float m = fmaxf(a, b);
    float d = fabsf(a - b);
    return m + log1pf(__expf(-d));
}

// -------- kernel 0: W1 f32 [K=512][N=512] -> W1T bf16 [N][K] --------
__global__ __launch_bounds__(256) void transpose_cvt(const float* __restrict__ in,
                                                     u16* __restrict__ out) {
    __shared__ float tile[32][33];
    int tx = threadIdx.x, ty = threadIdx.y;
    int x = blockIdx.x * 32 + tx;          // n
    int y0 = blockIdx.y * 32 + ty;         // k
    for (int i = 0; i < 32; i += 8)
        tile[ty + i][tx] = in[(size_t)(y0 + i) * 512 + x];
    __syncthreads();
    int x2 = blockIdx.y * 32 + tx;         // k
    int y2 = blockIdx.x * 32 + ty;         // n
    for (int i = 0; i < 32; i += 8)
        out[(size_t)(y2 + i) * 512 + x2] = f2bf(tile[tx][ty + i]);
}

// -------- kernel 1: fused MLP o = tanh(FM@W1+b1)@W2+b2 --------
// block: 256 threads (4 waves, 2x2), tile 128 rows x (4 chunks of 128 cols), BK=32
#define LDST 40   // padded LDS row stride (elems): 8-way bank conflict -> free 2-way

__global__ __launch_bounds__(256) void mlp_fused(
    const float* __restrict__ FM, const u16* __restrict__ W1T,
    const float* __restrict__ b1, const float* __restrict__ W2,
    const float* __restrict__ b2, float* __restrict__ o_buf) {

    __shared__ __align__(16) u16 ldsA[128 * LDST];
    __shared__ __align__(16) u16 ldsB[128 * LDST];
    __shared__ float ldsO[128][2][2];   // [row][wx][j]

    const int tid  = threadIdx.x;
    const int wave = tid >> 6;
    const int lane = tid & 63;
    const int wy = wave >> 1, wx = wave & 1;
    const int col = lane & 15;     // fragment row/col within 16
    const int g   = lane >> 4;     // k-group
    const size_t row0 = (size_t)blockIdx.x * 128;

    const int sr = tid >> 1;            // staging row 0..127
    const int sh = (tid & 1) * 16;      // staging k-offset 0 or 16

    float po[4][4][2];
#pragma unroll
    for (int mi = 0; mi < 4; mi++)
#pragma unroll
        for (int r = 0; r < 4; r++) { po[mi][r][0] = 0.f; po[mi][r][1] = 0.f; }

    for (int nc = 0; nc < 4; ++nc) {
        floatx4 acc[4][4];
        floatx4 zero = {0.f, 0.f, 0.f, 0.f};
#pragma unroll
        for (int mi = 0; mi < 4; mi++)
#pragma unroll
            for (int ni = 0; ni < 4; ni++) acc[mi][ni] = zero;

        for (int ks = 0; ks < 16; ++ks) {
            const int k0 = ks * 32;
            __syncthreads();
            {   // A tile: 128 rows x 32 k, f32 -> bf16
                const float* src = FM + (row0 + sr) * 512 + k0 + sh;
                float4 f0 = ((const float4*)src)[0];
                float4 f1 = ((const float4*)src)[1];
                float4 f2 = ((const float4*)src)[2];
                float4 f3 = ((const float4*)src)[3];
                union { uint4 v; u16 s[8]; } p0, p1;
                p0.s[0] = f2bf(f0.x); p0.s[1] = f2bf(f0.y);
                p0.s[2] = f2bf(f0.z); p0.s[3] = f2bf(f0.w);
                p0.s[4] = f2bf(f1.x); p0.s[5] = f2bf(f1.y);
                p0.s[6] = f2bf(f1.z); p0.s[7] = f2bf(f1.w);
                p1.s[0] = f2bf(f2.x); p1.s[1] = f2bf(f2.y);
                p1.s[2] = f2bf(f2.z); p1.s[3] = f2bf(f2.w);
                p1.s[4] = f2bf(f3.x); p1.s[5] = f2bf(f3.y);
                p1.s[6] = f2bf(f3.z); p1.s[7] = f2bf(f3.w);
                *(uint4*)(ldsA + sr * LDST + sh)     = p0.v;
                *(uint4*)(ldsA + sr * LDST + sh + 8) = p1.v;
            }
            {   // B tile: 128 rows x 32 k, bf16 direct
                const u16* src = W1T + (size_t)(nc * 128 + sr) * 512 + k0 + sh;
                *(uint4*)(ldsB + sr * LDST + sh)     = ((const uint4*)src)[0];
                *(uint4*)(ldsB + sr * LDST + sh + 8) = ((const uint4*)src)[1];
            }
            __syncthreads();
            bf16x8 afr[4], bfr[4];
#pragma unroll
            for (int mi = 0; mi < 4; mi++)
                afr[mi] = *(const bf16x8*)(ldsA + (wy * 64 + mi * 16 + col) * LDST + g * 8);
#pragma unroll
            for (int ni = 0; ni < 4; ni++)
                bfr[ni] = *(const bf16x8*)(ldsB + (wx * 64 + ni * 16 + col) * LDST + g * 8);
#pragma unroll
            for (int mi = 0; mi < 4; mi++)
#pragma unroll
                for (int ni = 0; ni < 4; ni++)
                    acc[mi][ni] = __builtin_amdgcn_mfma_f32_16x16x32_bf16(
                        afr[mi], bfr[ni], acc[mi][ni], 0, 0, 0);
        }

        // chunk epilogue: h = tanh(acc + b1[n]); fold into W2 reduction
#pragma unroll
        for (int ni = 0; ni < 4; ni++) {
            int n = nc * 128 + wx * 64 + ni * 16 + col;
            float b1f = b1[n];
            float w20 = W2[2 * n], w21 = W2[2 * n + 1];
#pragma unroll
            for (int mi = 0; mi < 4; mi++)
#pragma unroll
                for (int r = 0; r < 4; r++) {
                    float x = acc[mi][ni][r] + b1f;
                    float ax = fabsf(x);
                    float e = __expf(-2.f * ax);
                    float t = (1.f - e) / (1.f + e);   // tanh(|x|), overflow-safe
                    float h = copysignf(t, x);
                    po[mi][r][0] += h * w20;
                    po[mi][r][1] += h * w21;
                }
        }
    }

    // reduce po across the 16 cols (xor over lane bits 0..3)
#pragma unroll
    for (int mi = 0; mi < 4; mi++)
#pragma unroll
        for (int r = 0; r < 4; r++)
#pragma unroll
            for (int j = 0; j < 2; j++) {
                float v = po[mi][r][j];
                v += __shfl_xor(v, 1, 64);
                v += __shfl_xor(v, 2, 64);
                v += __shfl_xor(v, 4, 64);
                v += __shfl_xor(v, 8, 64);
                po[mi][r][j] = v;
            }
    __syncthreads();
    if (col == 0) {
#pragma unroll
        for (int mi = 0; mi < 4; mi++)
#pragma unroll
            for (int r = 0; r < 4; r++) {
                int row = wy * 64 + mi * 16 + g * 4 + r;
                ldsO[row][wx][0] = po[mi][r][0];
                ldsO[row][wx][1] = po[mi][r][1];
            }
    }
    __syncthreads();
    {   // 128 rows x 2 outputs = 256 = blockDim
        int row = tid >> 1, j = tid & 1;
        float v = ldsO[row][0][j] + ldsO[row][1][j] + b2[j];
        o_buf[(row0 + row) * 2 + j] = v;
    }
}

// -------- kernel 2: per-(b,chain) HMM recurrence --------
__global__ __launch_bounds__(512) void bkt_scan(
    const int* __restrict__ corr, const int* __restrict__ kc,
    const float* __restrict__ trans_logits,
    const float* __restrict__ obs_logits,
    const float* __restrict__ init_logits,
    const float* __restrict__ o_buf,
    float* __restrict__ out) {

    __shared__ int s_kc[T_SZ];
    __shared__ int s_corr[T_SZ];
    __shared__ float2 s_o[T_SZ];
    const int b = blockIdx.x;

    for (int t = threadIdx.x; t < T_SZ; t += 512) {
        s_kc[t] = kc[b * T_SZ + t];
        s_corr[t] = corr[b * T_SZ + t];
        s_o[t] = ((const float2*)o_buf)[b * T_SZ + t];
    }
    __syncthreads();

    const int c = threadIdx.x;
    if (c >= NK) return;

    float ob00 = obs_logits[c * 4 + 0], ob01 = obs_logits[c * 4 + 1];
    float ob10 = obs_logits[c * 4 + 2], ob11 = obs_logits[c * 4 + 3];
    float tr00 = trans_logits[c * 4 + 0], tr01 = trans_logits[c * 4 + 1];
    float tr10 = trans_logits[c * 4 + 2], tr11 = trans_logits[c * 4 + 3];
    // log_softmax over i (dim 1): lt[i][j] = tr[i][j] - lse_i(tr[:,j])
    float n0 = lse2(tr00, tr10), n1 = lse2(tr01, tr11);
    float lt00 = tr00 - n0, lt01 = tr01 - n1;
    float lt10 = tr10 - n0, lt11 = tr11 - n1;
    float i0 = init_logits[c * 2], i1 = init_logits[c * 2 + 1];
    float ni = lse2(i0, i1);
    float la0 = i0 - ni, la1 = i1 - ni;

    for (int t = 0; t < T_SZ; ++t) {
        if (s_kc[t] == c) {
            float o0 = s_o[t].x, o1 = s_o[t].y;
            // x[s][z] = obs[s][z] + (z==0 ? o_s : -o_s); log_softmax over z
            float x00 = ob00 + o0, x01 = ob01 - o0;
            float x10 = ob10 + o1, x11 = ob11 - o1;
            float d0 = lse2(x00, x01), d1 = lse2(x10, x11);
            float lo00 = x00 - d0, lo01 = x01 - d0;
            float lo10 = x10 - d1, lo11 = x11 - d1;
            // log_py[z] = lse_s(lo[s][z] + la[s]), normalized over z
            float py0 = lse2(lo00 + la0, lo10 + la1);
            float py1 = lse2(lo01 + la0, lo11 + la1);
            float pn = lse2(py0, py1);
            float2 res = make_float2(py0 - pn, py1 - pn);
            ((float2*)out)[b * T_SZ + t] = res;
            // state update
            float lp0 = s_corr[t] ? lo01 : lo00;
            float lp1 = s_corr[t] ? lo11 : lo10;
            float t0 = lp0 + la0, t1 = lp1 + la1;
            float nla0 = lse2(t0 + lt00, t1 + lt01);
            float nla1 = lse2(t0 + lt10, t1 + lt11);
            la0 = nla0; la1 = nla1;
        }
    }
}

extern "C" void kernel_launch(void* const* d_in, const int* in_sizes, int n_in,
                              void* d_out, int out_size, void* d_ws, size_t ws_size,
                              hipStream_t stream) {
    const int*   corr = (const int*)d_in[0];
    const int*   kc   = (const int*)d_in[1];
    const float* FM   = (const float*)d_in[2];
    const float* W1   = (const float*)d_in[3];
    const float* b1   = (const float*)d_in[4];
    const float* W2   = (const float*)d_in[5];
    const float* b2   = (const float*)d_in[6];
    const float* trans_logits = (const float*)d_in[7];
    const float* obs_logits   = (const float*)d_in[8];
    const float* init_logits  = (const float*)d_in[9];
    float* out = (float*)d_out;   // reference output dtype: float32

    u16*   w1t   = (u16*)d_ws;                                  // 512*512 bf16 = 512 KB
    float* o_buf = (float*)((char*)d_ws + 512 * 512 * 2);       // 65536*2 f32 = 512 KB

    transpose_cvt<<<dim3(16, 16), dim3(32, 8), 0, stream>>>(W1, w1t);
    mlp_fused<<<512, 256, 0, stream>>>(FM, w1t, b1, W2, b2, o_buf);
    bkt_scan<<<B_SZ, 512, 0, stream>>>(corr, kc, trans_logits, obs_logits,
                                       init_logits, o_buf, out);
}

// Round 5
// 329.112 us; speedup vs baseline: 2.4727x; 2.4727x over previous
//
#include <hip/hip_runtime.h>
#include <hip/hip_bf16.h>
#include <stdint.h>

typedef unsigned short u16;
typedef __bf16 bf16x8 __attribute__((ext_vector_type(8)));
typedef float floatx4 __attribute__((ext_vector_type(4)));

#define B_SZ 64
#define T_SZ 1024
#define NK 500

// f32 -> bf16, round-to-nearest-even
__device__ __forceinline__ u16 f2bf(float f) {
    union { float f; uint32_t u; } v; v.f = f;
    uint32_t u = v.u;
    u += 0x7FFFu + ((u >> 16) & 1u);
    return (u16)(u >> 16);
}

// HW transcendentals: v_exp_f32 (2^x), v_log_f32 (log2 x)
__device__ __forceinline__ float exp2_hw(float x) { return __builtin_amdgcn_exp2f(x); }
__device__ __forceinline__ float log2_hw(float x) { return __builtin_amdgcn_logf(x); }

// fast stable 2-way logsumexp
__device__ __forceinline__ float lse2(float a, float b) {
    float m = fmaxf(a, b);
    float d = fabsf(a - b);
    // m + ln2 * log2(1 + 2^(-d*log2e))
    return fmaf(0.6931471805599453f,
                log2_hw(1.0f + exp2_hw(-d * 1.4426950408889634f)), m);
}

// async global->LDS, 16 bytes per lane (LDS dest must be uniform-base + lane*16)
__device__ __forceinline__ void load_lds16(const void* g, void* s) {
    __builtin_amdgcn_global_load_lds(
        (const __attribute__((address_space(1))) void*)g,
        (__attribute__((address_space(3))) void*)s, 16, 0, 0);
}

// -------- kernel 0: W1 f32 [K=512][N=512] -> W1T bf16 [N][K] --------
__global__ __launch_bounds__(256) void transpose_cvt(const float* __restrict__ in,
                                                     u16* __restrict__ out) {
    __shared__ float tile[32][33];
    int tx = threadIdx.x, ty = threadIdx.y;
    int x = blockIdx.x * 32 + tx;          // n
    int y0 = blockIdx.y * 32 + ty;         // k
    for (int i = 0; i < 32; i += 8)
        tile[ty + i][tx] = in[(size_t)(y0 + i) * 512 + x];
    __syncthreads();
    int x2 = blockIdx.y * 32 + tx;         // k
    int y2 = blockIdx.x * 32 + ty;         // n
    for (int i = 0; i < 32; i += 8)
        out[(size_t)(y2 + i) * 512 + x2] = f2bf(tile[tx][ty + i]);
}

// -------- kernel 1: fused MLP o = tanh(FM@W1+b1)@W2+b2 --------
// 1024 blocks x 256 thr (4 waves). Block = 64 rows; A (64x512 bf16, 64 KB,
// xor-swizzled) staged+converted ONCE; B streamed per-ks (16 KB, fragment
// order, global_load_lds w=16). N=512 in 2 chunks of 256 (wave tile 64x64).
__global__ __launch_bounds__(256, 2) void mlp_fused(
    const float* __restrict__ FM, const u16* __restrict__ W1T,
    const float* __restrict__ b1, const float* __restrict__ W2,
    const float* __restrict__ b2, float* __restrict__ o_buf) {

    __shared__ __align__(16) u16 ldsA[64 * 512];   // 64 KB, swizzle: k8 ^= (row&7)
    __shared__ __align__(16) u16 ldsB[256 * 32];   // 16 KB, [nb16][g][col][8]
    float* ldsO = (float*)ldsB;                    // aliased after last B use

    const int tid  = threadIdx.x;
    const int w    = tid >> 6;       // wave 0..3
    const int lane = tid & 63;
    const int col  = lane & 15;
    const int g    = lane >> 4;
    const size_t row0 = (size_t)blockIdx.x * 64;

    // ---- stage A once: 64 rows x 512 k, f32 -> bf16, xor-swizzled ----
#pragma unroll
    for (int i = 0; i < 16; ++i) {
        int flat = i * 256 + tid;        // 8-elem group index, 0..4095
        int row  = flat >> 6;            // 0..63
        int k8   = flat & 63;            // 0..63
        const float* src = FM + (row0 + row) * 512 + k8 * 8;
        float4 f0 = ((const float4*)src)[0];
        float4 f1 = ((const float4*)src)[1];
        union { uint4 v; u16 s[8]; } p;
        p.s[0] = f2bf(f0.x); p.s[1] = f2bf(f0.y);
        p.s[2] = f2bf(f0.z); p.s[3] = f2bf(f0.w);
        p.s[4] = f2bf(f1.x); p.s[5] = f2bf(f1.y);
        p.s[6] = f2bf(f1.z); p.s[7] = f2bf(f1.w);
        int sw = k8 ^ (row & 7);
        *(uint4*)(ldsA + row * 512 + sw * 8) = p.v;
    }

    float po[4][4][2];
#pragma unroll
    for (int mi = 0; mi < 4; mi++)
#pragma unroll
        for (int r = 0; r < 4; r++) { po[mi][r][0] = 0.f; po[mi][r][1] = 0.f; }

    for (int chunk = 0; chunk < 2; ++chunk) {
        floatx4 acc[4][4];
        floatx4 zero = {0.f, 0.f, 0.f, 0.f};
#pragma unroll
        for (int mi = 0; mi < 4; mi++)
#pragma unroll
            for (int ni = 0; ni < 4; ni++) acc[mi][ni] = zero;

        for (int ks = 0; ks < 16; ++ks) {
            // stage B: 256 n-rows x 32 k, fragment order, lane-linear LDS
#pragma unroll
            for (int j = 0; j < 4; ++j) {
                int idx = j * 256 + tid;       // 16B-group index 0..1023
                int nb  = idx >> 6;            // 0..15
                int gg  = (idx >> 4) & 3;
                int cc  = idx & 15;
                const u16* gsrc = W1T + (size_t)(chunk * 256 + nb * 16 + cc) * 512
                                       + ks * 32 + gg * 8;
                load_lds16(gsrc, ldsB + idx * 8);
            }
            __syncthreads();   // drains vmcnt (global_load_lds) + A ds_writes

            bf16x8 afr[4], bfr[4];
#pragma unroll
            for (int mi = 0; mi < 4; mi++) {
                int sw = (ks * 4 + g) ^ (col & 7);   // row&7 == col&7 (rows mi*16+col)
                afr[mi] = *(const bf16x8*)(ldsA + (mi * 16 + col) * 512 + sw * 8);
            }
#pragma unroll
            for (int ni = 0; ni < 4; ni++)
                bfr[ni] = *(const bf16x8*)(ldsB + ((w * 4 + ni) * 64 + g * 16 + col) * 8);
#pragma unroll
            for (int mi = 0; mi < 4; mi++)
#pragma unroll
                for (int ni = 0; ni < 4; ni++)
                    acc[mi][ni] = __builtin_amdgcn_mfma_f32_16x16x32_bf16(
                        afr[mi], bfr[ni], acc[mi][ni], 0, 0, 0);
            __syncthreads();   // B reads done before next-ks overwrite
        }

        // chunk epilogue: h = tanh(acc + b1[n]); fold into W2 reduction
#pragma unroll
        for (int ni = 0; ni < 4; ni++) {
            int n = chunk * 256 + w * 64 + ni * 16 + col;
            float b1f = b1[n];
            float w20 = W2[2 * n], w21 = W2[2 * n + 1];
#pragma unroll
            for (int mi = 0; mi < 4; mi++)
#pragma unroll
                for (int r = 0; r < 4; r++) {
                    float x = acc[mi][ni][r] + b1f;
                    float ax = fabsf(x);
                    float e = exp2_hw(-2.885390082f * ax);   // exp(-2ax)
                    float t = (1.f - e) / (1.f + e);
                    float h = copysignf(t, x);
                    po[mi][r][0] += h * w20;
                    po[mi][r][1] += h * w21;
                }
        }
    }

    // reduce po over the 16 cols (lane bits 0..3)
#pragma unroll
    for (int mi = 0; mi < 4; mi++)
#pragma unroll
        for (int r = 0; r < 4; r++)
#pragma unroll
            for (int j = 0; j < 2; j++) {
                float v = po[mi][r][j];
                v += __shfl_xor(v, 1, 64);
                v += __shfl_xor(v, 2, 64);
                v += __shfl_xor(v, 4, 64);
                v += __shfl_xor(v, 8, 64);
                po[mi][r][j] = v;
            }
    __syncthreads();           // last B frag reads complete before aliasing as ldsO
    if (col == 0) {
#pragma unroll
        for (int mi = 0; mi < 4; mi++)
#pragma unroll
            for (int r = 0; r < 4; r++) {
                int row = mi * 16 + g * 4 + r;      // 0..63
                ldsO[(row * 4 + w) * 2 + 0] = po[mi][r][0];
                ldsO[(row * 4 + w) * 2 + 1] = po[mi][r][1];
            }
    }
    __syncthreads();
    if (tid < 128) {           // 64 rows x 2 outputs
        int row = tid >> 1, j = tid & 1;
        float v = ldsO[(row * 4 + 0) * 2 + j] + ldsO[(row * 4 + 1) * 2 + j]
                + ldsO[(row * 4 + 2) * 2 + j] + ldsO[(row * 4 + 3) * 2 + j] + b2[j];
        o_buf[(row0 + row) * 2 + j] = v;
    }
}

// -------- kernel 2: per-(b,chain) HMM recurrence, ballot-mask driven --------
// grid 64*8 blocks of 64 threads: block (b, g) owns chains c = g*64+lane.
__global__ __launch_bounds__(64) void bkt_scan(
    const int* __restrict__ corr, const int* __restrict__ kc,
    const float* __restrict__ trans_logits,
    const float* __restrict__ obs_logits,
    const float* __restrict__ init_logits,
    const float* __restrict__ o_buf,
    float* __restrict__ out) {

    __shared__ int s_kc[T_SZ];
    __shared__ int s_corr[T_SZ];
    __shared__ float2 s_o[T_SZ];
    const int b = blockIdx.x >> 3;
    const int g = blockIdx.x & 7;
    const int lane = threadIdx.x;

#pragma unroll
    for (int i = 0; i < 4; ++i) {
        int t4 = i * 64 + lane;   // int4 group
        ((int4*)s_kc)[t4]   = ((const int4*)(kc + b * T_SZ))[t4];
        ((int4*)s_corr)[t4] = ((const int4*)(corr + b * T_SZ))[t4];
    }
#pragma unroll
    for (int i = 0; i < 8; ++i) {
        int t4 = i * 64 + lane;   // float4 group (2 timesteps)
        ((float4*)s_o)[t4] = ((const float4*)(o_buf + (size_t)b * T_SZ * 2))[t4];
    }
    __syncthreads();

    const int c  = g * 64 + lane;
    const int cp = c < NK ? c : NK - 1;    // clamp for param loads (lanes c>=500 inert)

    float ob00 = obs_logits[cp * 4 + 0], ob01 = obs_logits[cp * 4 + 1];
    float ob10 = obs_logits[cp * 4 + 2], ob11 = obs_logits[cp * 4 + 3];
    float tr00 = trans_logits[cp * 4 + 0], tr01 = trans_logits[cp * 4 + 1];
    float tr10 = trans_logits[cp * 4 + 2], tr11 = trans_logits[cp * 4 + 3];
    float n0 = lse2(tr00, tr10), n1 = lse2(tr01, tr11);
    float lt00 = tr00 - n0, lt01 = tr01 - n1;
    float lt10 = tr10 - n0, lt11 = tr11 - n1;
    float i0 = init_logits[cp * 2], i1 = init_logits[cp * 2 + 1];
    float nli = lse2(i0, i1);
    float la0 = i0 - nli, la1 = i1 - nli;

    for (int w16 = 0; w16 < 16; ++w16) {
        int tl = w16 * 64 + lane;
        unsigned long long mask = __ballot((s_kc[tl] >> 6) == g);
        while (mask) {
            int tz = __builtin_ctzll(mask);
            mask &= mask - 1;
            int t = w16 * 64 + tz;
            int kct = s_kc[t];
            if (c == kct) {
                float o0 = s_o[t].x, o1 = s_o[t].y;
                float x00 = ob00 + o0, x01 = ob01 - o0;
                float x10 = ob10 + o1, x11 = ob11 - o1;
                float d0 = lse2(x00, x01), d1 = lse2(x10, x11);
                float lo00 = x00 - d0, lo01 = x01 - d0;
                float lo10 = x10 - d1, lo11 = x11 - d1;
                float py0 = lse2(lo00 + la0, lo10 + la1);
                float py1 = lse2(lo01 + la0, lo11 + la1);
                float pn = lse2(py0, py1);
                ((float2*)out)[(size_t)b * T_SZ + t] = make_float2(py0 - pn, py1 - pn);
                float lp0 = s_corr[t] ? lo01 : lo00;
                float lp1 = s_corr[t] ? lo11 : lo10;
                float t0 = lp0 + la0, t1 = lp1 + la1;
                float nla0 = lse2(t0 + lt00, t1 + lt01);
                float nla1 = lse2(t0 + lt10, t1 + lt11);
                la0 = nla0; la1 = nla1;
            }
        }
    }
}

extern "C" void kernel_launch(void* const* d_in, const int* in_sizes, int n_in,
                              void* d_out, int out_size, void* d_ws, size_t ws_size,
                              hipStream_t stream) {
    const int*   corr = (const int*)d_in[0];
    const int*   kc   = (const int*)d_in[1];
    const float* FM   = (const float*)d_in[2];
    const float* W1   = (const float*)d_in[3];
    const float* b1   = (const float*)d_in[4];
    const float* W2   = (const float*)d_in[5];
    const float* b2   = (const float*)d_in[6];
    const float* trans_logits = (const float*)d_in[7];
    const float* obs_logits   = (const float*)d_in[8];
    const float* init_logits  = (const float*)d_in[9];
    float* out = (float*)d_out;

    u16*   w1t   = (u16*)d_ws;                                  // 512 KB
    float* o_buf = (float*)((char*)d_ws + 512 * 512 * 2);       // 512 KB

    transpose_cvt<<<dim3(16, 16), dim3(32, 8), 0, stream>>>(W1, w1t);
    mlp_fused<<<1024, 256, 0, stream>>>(FM, w1t, b1, W2, b2, o_buf);
    bkt_scan<<<B_SZ * 8, 64, 0, stream>>>(corr, kc, trans_logits, obs_logits,
                                          init_logits, o_buf, out);
}

// Round 6
// 326.280 us; speedup vs baseline: 2.4942x; 1.0087x over previous
//
#include <hip/hip_runtime.h>
#include <hip/hip_bf16.h>
#include <stdint.h>

typedef unsigned short u16;
typedef __bf16 bf16x8 __attribute__((ext_vector_type(8)));
typedef float floatx4 __attribute__((ext_vector_type(4)));

#define B_SZ 64
#define T_SZ 1024
#define NK 500

// f32 -> bf16, round-to-nearest-even
__device__ __forceinline__ u16 f2bf(float f) {
    union { float f; uint32_t u; } v; v.f = f;
    uint32_t u = v.u;
    u += 0x7FFFu + ((u >> 16) & 1u);
    return (u16)(u >> 16);
}

// HW transcendentals: v_exp_f32 (2^x), v_log_f32 (log2 x)
__device__ __forceinline__ float exp2_hw(float x) { return __builtin_amdgcn_exp2f(x); }
__device__ __forceinline__ float log2_hw(float x) { return __builtin_amdgcn_logf(x); }

// fast stable 2-way logsumexp
__device__ __forceinline__ float lse2(float a, float b) {
    float m = fmaxf(a, b);
    float d = fabsf(a - b);
    return fmaf(0.6931471805599453f,
                log2_hw(1.0f + exp2_hw(-d * 1.4426950408889634f)), m);
}

// -------- kernel 0: W1 f32 [K=512][N=512] -> W1T bf16 [N][K] --------
__global__ __launch_bounds__(256) void transpose_cvt(const float* __restrict__ in,
                                                     u16* __restrict__ out) {
    __shared__ float tile[32][33];
    int tx = threadIdx.x, ty = threadIdx.y;
    int x = blockIdx.x * 32 + tx;          // n
    int y0 = blockIdx.y * 32 + ty;         // k
    for (int i = 0; i < 32; i += 8)
        tile[ty + i][tx] = in[(size_t)(y0 + i) * 512 + x];
    __syncthreads();
    int x2 = blockIdx.y * 32 + tx;         // k
    int y2 = blockIdx.x * 32 + ty;         // n
    for (int i = 0; i < 32; i += 8)
        out[(size_t)(y2 + i) * 512 + x2] = f2bf(tile[tx][ty + i]);
}

// -------- kernel 1: fused MLP o = tanh(FM@W1+b1)@W2+b2 --------
// 1024 blocks x 256 thr (4 waves). Block = 64 rows. A (64x512 bf16, 64 KB,
// xor-swizzled LDS) staged+converted ONCE. B (W1T, 512 KB, L2-resident) is
// loaded straight into VGPRs per-ks (double-buffered) -> NO barriers in the
// K-loop (the round-5 profile showed per-ks vmcnt(0)+s_barrier drains left
// MfmaUtil at 10%). Wave tile 64 x 128 (acc 4x8), single N pass.
__global__ __launch_bounds__(256, 2) void mlp_fused(
    const float* __restrict__ FM, const u16* __restrict__ W1T,
    const float* __restrict__ b1, const float* __restrict__ W2,
    const float* __restrict__ b2, float* __restrict__ o_buf) {

    __shared__ __align__(16) u16 ldsA[64 * 512];   // 64 KB, swizzle: k8 ^= (row&7)
    __shared__ float ldsO[64][4][2];               // 2 KB

    const int tid  = threadIdx.x;
    const int w    = tid >> 6;       // wave 0..3
    const int lane = tid & 63;
    const int col  = lane & 15;
    const int g    = lane >> 4;
    const size_t row0 = (size_t)blockIdx.x * 64;

    // ---- stage A once: 64 rows x 512 k, f32 -> bf16, xor-swizzled ----
#pragma unroll
    for (int i = 0; i < 16; ++i) {
        int flat = i * 256 + tid;        // 8-elem group index, 0..4095
        int row  = flat >> 6;            // 0..63
        int k8   = flat & 63;            // 0..63
        const float* src = FM + (row0 + row) * 512 + k8 * 8;
        float4 f0 = ((const float4*)src)[0];
        float4 f1 = ((const float4*)src)[1];
        union { uint4 v; u16 s[8]; } p;
        p.s[0] = f2bf(f0.x); p.s[1] = f2bf(f0.y);
        p.s[2] = f2bf(f0.z); p.s[3] = f2bf(f0.w);
        p.s[4] = f2bf(f1.x); p.s[5] = f2bf(f1.y);
        p.s[6] = f2bf(f1.z); p.s[7] = f2bf(f1.w);
        int sw = k8 ^ (row & 7);
        *(uint4*)(ldsA + row * 512 + sw * 8) = p.v;
    }
    __syncthreads();   // the ONLY barrier before the epilogue

    // per-lane B base: rows n = w*128 + ni*16 + col, k-offset g*8
    const u16* bbase = W1T + (size_t)(w * 128 + col) * 512 + g * 8;

    floatx4 acc[4][8];
    floatx4 zero = {0.f, 0.f, 0.f, 0.f};
#pragma unroll
    for (int mi = 0; mi < 4; mi++)
#pragma unroll
        for (int ni = 0; ni < 8; ni++) acc[mi][ni] = zero;

    bf16x8 bA[8], bB[8];
#pragma unroll
    for (int ni = 0; ni < 8; ni++)
        bA[ni] = *(const bf16x8*)(bbase + ni * 16 * 512);          // ks=0

    for (int ks2 = 0; ks2 < 16; ks2 += 2) {
        // prefetch ks2+1 into bB
#pragma unroll
        for (int ni = 0; ni < 8; ni++)
            bB[ni] = *(const bf16x8*)(bbase + ni * 16 * 512 + (ks2 + 1) * 32);
        {   // compute ks2 with bA
            bf16x8 afr[4];
            int sw = (ks2 * 4 + g) ^ (col & 7);
#pragma unroll
            for (int mi = 0; mi < 4; mi++)
                afr[mi] = *(const bf16x8*)(ldsA + (mi * 16 + col) * 512 + sw * 8);
#pragma unroll
            for (int mi = 0; mi < 4; mi++)
#pragma unroll
                for (int ni = 0; ni < 8; ni++)
                    acc[mi][ni] = __builtin_amdgcn_mfma_f32_16x16x32_bf16(
                        afr[mi], bA[ni], acc[mi][ni], 0, 0, 0);
        }
        // prefetch ks2+2 into bA (clamped; ks2+2==16 reload of k=0 is harmless)
        int ksn = (ks2 + 2) & 15;
#pragma unroll
        for (int ni = 0; ni < 8; ni++)
            bA[ni] = *(const bf16x8*)(bbase + ni * 16 * 512 + ksn * 32);
        {   // compute ks2+1 with bB
            bf16x8 afr[4];
            int sw = ((ks2 + 1) * 4 + g) ^ (col & 7);
#pragma unroll
            for (int mi = 0; mi < 4; mi++)
                afr[mi] = *(const bf16x8*)(ldsA + (mi * 16 + col) * 512 + sw * 8);
#pragma unroll
            for (int mi = 0; mi < 4; mi++)
#pragma unroll
                for (int ni = 0; ni < 8; ni++)
                    acc[mi][ni] = __builtin_amdgcn_mfma_f32_16x16x32_bf16(
                        afr[mi], bB[ni], acc[mi][ni], 0, 0, 0);
        }
    }

    // epilogue: h = tanh(acc + b1[n]); fold into W2 reduction
    float po[4][4][2];
#pragma unroll
    for (int mi = 0; mi < 4; mi++)
#pragma unroll
        for (int r = 0; r < 4; r++) { po[mi][r][0] = 0.f; po[mi][r][1] = 0.f; }

#pragma unroll
    for (int ni = 0; ni < 8; ni++) {
        int n = w * 128 + ni * 16 + col;
        float b1f = b1[n];
        float w20 = W2[2 * n], w21 = W2[2 * n + 1];
#pragma unroll
        for (int mi = 0; mi < 4; mi++)
#pragma unroll
            for (int r = 0; r < 4; r++) {
                float x = acc[mi][ni][r] + b1f;
                float ax = fabsf(x);
                float e = exp2_hw(-2.885390082f * ax);   // exp(-2ax)
                float t = (1.f - e) / (1.f + e);
                float h = copysignf(t, x);
                po[mi][r][0] += h * w20;
                po[mi][r][1] += h * w21;
            }
    }

    // reduce po over the 16 cols (lane bits 0..3)
#pragma unroll
    for (int mi = 0; mi < 4; mi++)
#pragma unroll
        for (int r = 0; r < 4; r++)
#pragma unroll
            for (int j = 0; j < 2; j++) {
                float v = po[mi][r][j];
                v += __shfl_xor(v, 1, 64);
                v += __shfl_xor(v, 2, 64);
                v += __shfl_xor(v, 4, 64);
                v += __shfl_xor(v, 8, 64);
                po[mi][r][j] = v;
            }
    if (col == 0) {
#pragma unroll
        for (int mi = 0; mi < 4; mi++)
#pragma unroll
            for (int r = 0; r < 4; r++) {
                int row = mi * 16 + g * 4 + r;      // 0..63
                ldsO[row][w][0] = po[mi][r][0];
                ldsO[row][w][1] = po[mi][r][1];
            }
    }
    __syncthreads();
    if (tid < 128) {           // 64 rows x 2 outputs
        int row = tid >> 1, j = tid & 1;
        float v = ldsO[row][0][j] + ldsO[row][1][j]
                + ldsO[row][2][j] + ldsO[row][3][j] + b2[j];
        o_buf[(row0 + row) * 2 + j] = v;
    }
}

// -------- kernel 2: per-(b,chain) HMM recurrence, ballot-mask driven --------
// grid 64*8 blocks of 64 threads: block (b, g) owns chains c = g*64+lane.
__global__ __launch_bounds__(64) void bkt_scan(
    const int* __restrict__ corr, const int* __restrict__ kc,
    const float* __restrict__ trans_logits,
    const float* __restrict__ obs_logits,
    const float* __restrict__ init_logits,
    const float* __restrict__ o_buf,
    float* __restrict__ out) {

    __shared__ int s_kc[T_SZ];
    __shared__ int s_corr[T_SZ];
    __shared__ float2 s_o[T_SZ];
    const int b = blockIdx.x >> 3;
    const int g = blockIdx.x & 7;
    const int lane = threadIdx.x;

#pragma unroll
    for (int i = 0; i < 4; ++i) {
        int t4 = i * 64 + lane;   // int4 group
        ((int4*)s_kc)[t4]   = ((const int4*)(kc + b * T_SZ))[t4];
        ((int4*)s_corr)[t4] = ((const int4*)(corr + b * T_SZ))[t4];
    }
#pragma unroll
    for (int i = 0; i < 8; ++i) {
        int t4 = i * 64 + lane;   // float4 group (2 timesteps)
        ((float4*)s_o)[t4] = ((const float4*)(o_buf + (size_t)b * T_SZ * 2))[t4];
    }
    __syncthreads();

    const int c  = g * 64 + lane;
    const int cp = c < NK ? c : NK - 1;    // clamp for param loads (lanes c>=500 inert)

    float ob00 = obs_logits[cp * 4 + 0], ob01 = obs_logits[cp * 4 + 1];
    float ob10 = obs_logits[cp * 4 + 2], ob11 = obs_logits[cp * 4 + 3];
    float tr00 = trans_logits[cp * 4 + 0], tr01 = trans_logits[cp * 4 + 1];
    float tr10 = trans_logits[cp * 4 + 2], tr11 = trans_logits[cp * 4 + 3];
    float n0 = lse2(tr00, tr10), n1 = lse2(tr01, tr11);
    float lt00 = tr00 - n0, lt01 = tr01 - n1;
    float lt10 = tr10 - n0, lt11 = tr11 - n1;
    float i0 = init_logits[cp * 2], i1 = init_logits[cp * 2 + 1];
    float nli = lse2(i0, i1);
    float la0 = i0 - nli, la1 = i1 - nli;

    for (int w16 = 0; w16 < 16; ++w16) {
        int tl = w16 * 64 + lane;
        unsigned long long mask = __ballot((s_kc[tl] >> 6) == g);
        while (mask) {
            int tz = __builtin_ctzll(mask);
            mask &= mask - 1;
            int t = w16 * 64 + tz;
            int kct = s_kc[t];
            if (c == kct) {
                float o0 = s_o[t].x, o1 = s_o[t].y;
                float x00 = ob00 + o0, x01 = ob01 - o0;
                float x10 = ob10 + o1, x11 = ob11 - o1;
                float d0 = lse2(x00, x01), d1 = lse2(x10, x11);
                float lo00 = x00 - d0, lo01 = x01 - d0;
                float lo10 = x10 - d1, lo11 = x11 - d1;
                float py0 = lse2(lo00 + la0, lo10 + la1);
                float py1 = lse2(lo01 + la0, lo11 + la1);
                float pn = lse2(py0, py1);
                ((float2*)out)[(size_t)b * T_SZ + t] = make_float2(py0 - pn, py1 - pn);
                float lp0 = s_corr[t] ? lo01 : lo00;
                float lp1 = s_corr[t] ? lo11 : lo10;
                float t0 = lp0 + la0, t1 = lp1 + la1;
                float nla0 = lse2(t0 + lt00, t1 + lt01);
                float nla1 = lse2(t0 + lt10, t1 + lt11);
                la0 = nla0; la1 = nla1;
            }
        }
    }
}

extern "C" void kernel_launch(void* const* d_in, const int* in_sizes, int n_in,
                              void* d_out, int out_size, void* d_ws, size_t ws_size,
                              hipStream_t stream) {
    const int*   corr = (const int*)d_in[0];
    const int*   kc   = (const int*)d_in[1];
    const float* FM   = (const float*)d_in[2];
    const float* W1   = (const float*)d_in[3];
    const float* b1   = (const float*)d_in[4];
    const float* W2   = (const float*)d_in[5];
    const float* b2   = (const float*)d_in[6];
    const float* trans_logits = (const float*)d_in[7];
    const float* obs_logits   = (const float*)d_in[8];
    const float* init_logits  = (const float*)d_in[9];
    float* out = (float*)d_out;

    u16*   w1t   = (u16*)d_ws;                                  // 512 KB
    float* o_buf = (float*)((char*)d_ws + 512 * 512 * 2);       // 512 KB

    transpose_cvt<<<dim3(16, 16), dim3(32, 8), 0, stream>>>(W1, w1t);
    mlp_fused<<<1024, 256, 0, stream>>>(FM, w1t, b1, W2, b2, o_buf);
    bkt_scan<<<B_SZ * 8, 64, 0, stream>>>(corr, kc, trans_logits, obs_logits,
                                          init_logits, o_buf, out);
}